// Round 2
// baseline (319.627 us; speedup 1.0000x reference)
//
#include <hip/hip_runtime.h>
#include <hip/hip_bf16.h>
#include <stdint.h>

typedef short    s16x8  __attribute__((ext_vector_type(8)));
typedef __bf16   bf16x8 __attribute__((ext_vector_type(8)));
typedef float    f32x4  __attribute__((ext_vector_type(4)));

__device__ __forceinline__ unsigned short f2bf(float f) {
    union { float f; unsigned u; } v; v.f = f;
    unsigned r = v.u + 0x7FFFu + ((v.u >> 16) & 1u);
    return (unsigned short)(r >> 16);
}
__device__ __forceinline__ float bf2f(unsigned short s) {
    union { unsigned u; float f; } v; v.u = ((unsigned)s) << 16;
    return v.f;
}

__device__ __forceinline__ void gload16(const void* g, void* l) {
    __builtin_amdgcn_global_load_lds(
        (const __attribute__((address_space(1))) void*)(uintptr_t)g,
        (__attribute__((address_space(3))) void*)(uintptr_t)l,
        16, 0, 0);
}

// ---------------- fp32 -> bf16 conversion (vectorized, grid-stride) ----------
__global__ __launch_bounds__(256) void cvt_bf16(const float* __restrict__ in,
                                                unsigned short* __restrict__ out,
                                                int n4) {
    int i = blockIdx.x * blockDim.x + threadIdx.x;
    int stride = gridDim.x * blockDim.x;
    for (; i < n4; i += stride) {
        const float4 v = *(const float4*)(in + (size_t)i * 4);
        ushort4 o;
        o.x = f2bf(v.x); o.y = f2bf(v.y); o.z = f2bf(v.z); o.w = f2bf(v.w);
        *(ushort4*)(out + (size_t)i * 4) = o;
    }
}

// ---------------- 256x256 bf16 GEMM:  C = A[M][K] @ B[N][K]^T + bias --------
// 8 waves (2M x 4N), BK=32, double-buffered LDS (64 KiB), phase-split MFMA,
// counted vmcnt (T3+T4), XOR LDS swizzle both-sides (T2), setprio (T5),
// bijective XCD blockIdx swizzle (T1). Raw s_barrier only (no waitcnt drain).
template<int K, bool OUT_BF16>
__global__ __launch_bounds__(512, 2) void gemm256(
        const unsigned short* __restrict__ A,   // [M][K] bf16
        const unsigned short* __restrict__ B,   // [N][K] bf16
        const float* __restrict__ bias,         // [N] fp32
        void* __restrict__ Cvoid,               // [M][N] bf16 or fp32
        int M, int N, int ntn) {
    constexpr int BM = 256, BN = 256, BK = 32, NT = K / BK;
    __shared__ unsigned short As[2][BM * BK];   // 2 x 16 KiB
    __shared__ unsigned short Bs[2][BN * BK];   // 2 x 16 KiB
    const int tid  = threadIdx.x;
    const int lane = tid & 63;
    const int wv   = tid >> 6;
    // T1: bijective XCD swizzle (gridDim.x % 8 == 0 guaranteed by launcher)
    const int nwg = (int)gridDim.x;
    const int wg  = ((int)blockIdx.x & 7) * (nwg >> 3) + ((int)blockIdx.x >> 3);
    const int bm  = wg / ntn;
    const int bn  = wg % ntn;
    const int wr  = (wv >> 2) * 128;   // wave M-offset in tile
    const int wc  = (wv & 3) * 64;     // wave N-offset in tile
    const int lr  = lane & 15;
    const int ls  = lane >> 4;         // k-slot 0..3

    const unsigned short* Ag = A + (size_t)bm * BM * K;
    const unsigned short* Bg = B + (size_t)bn * BN * K;

    // Stage one 256x32 bf16 tile (16 KiB = 1024 x 16B chunks, 2 per thread).
    // LDS dest is linear (chunk c at byte c*16 -> wave-uniform base + lane*16);
    // the swizzle is applied on the GLOBAL source slot (rule #21).
    auto stage = [&](const unsigned short* G, unsigned short* lds) {
        #pragma unroll
        for (int p = 0; p < 2; ++p) {
            const int c     = p * 512 + tid;
            const int row   = c >> 2;            // 4 chunks (64B) per row
            const int slot  = c & 3;
            const int gslot = slot ^ ((row >> 1) & 3);   // T2 involution
            gload16(G + (size_t)row * K + gslot * 8, (char*)lds + c * 16);
        }
    };
    // Read one MFMA A/B fragment: logical slot = ls, physical = ls ^ swz(row).
    auto frag = [&](const unsigned short* lds, int row) -> bf16x8 {
        const int slot = ls ^ ((row >> 1) & 3);
        return *(const bf16x8*)((const char*)lds + row * (BK * 2) + slot * 16);
    };

    f32x4 acc[8][4] = {};

    stage(Ag, As[0]);
    stage(Bg, Bs[0]);          // 4 loads/thread outstanding (tile 0)

    #pragma unroll
    for (int t = 0; t < NT; ++t) {
        const int cur = t & 1;
        if (t + 1 < NT) {
            stage(Ag + (t + 1) * BK, As[cur ^ 1]);
            stage(Bg + (t + 1) * BK, Bs[cur ^ 1]);
            // oldest 4 (tile t) must land; tile t+1's 4 stay in flight
            asm volatile("s_waitcnt vmcnt(4)" ::: "memory");
        } else {
            asm volatile("s_waitcnt vmcnt(0)" ::: "memory");
        }
        __builtin_amdgcn_s_barrier();   // all waves' tile-t writes visible

        // ---- phase 1: C rows [wr, wr+64), all 4 n-frags ----
        bf16x8 a0[4], b0[4];
        #pragma unroll
        for (int m = 0; m < 4; ++m) a0[m] = frag(As[cur], wr + m * 16 + lr);
        #pragma unroll
        for (int n = 0; n < 4; ++n) b0[n] = frag(Bs[cur], wc + n * 16 + lr);
        __builtin_amdgcn_s_barrier();
        __builtin_amdgcn_s_setprio(1);
        #pragma unroll
        for (int m = 0; m < 4; ++m)
            #pragma unroll
            for (int n = 0; n < 4; ++n)
                acc[m][n] = __builtin_amdgcn_mfma_f32_16x16x32_bf16(
                    a0[m], b0[n], acc[m][n], 0, 0, 0);
        __builtin_amdgcn_s_setprio(0);
        __builtin_amdgcn_s_barrier();

        // ---- phase 2: C rows [wr+64, wr+128), reuse b0 ----
        bf16x8 a1[4];
        #pragma unroll
        for (int m = 0; m < 4; ++m) a1[m] = frag(As[cur], wr + 64 + m * 16 + lr);
        __builtin_amdgcn_s_barrier();
        __builtin_amdgcn_s_setprio(1);
        #pragma unroll
        for (int m = 0; m < 4; ++m)
            #pragma unroll
            for (int n = 0; n < 4; ++n)
                acc[4 + m][n] = __builtin_amdgcn_mfma_f32_16x16x32_bf16(
                    a1[m], b0[n], acc[4 + m][n], 0, 0, 0);
        __builtin_amdgcn_s_setprio(0);
        __builtin_amdgcn_s_barrier();   // end-of-iter: reads of As/Bs[cur] done
    }

    // epilogue: C/D layout col=lane&15, row=(lane>>4)*4+j (HW-verified)
    const int r0 = bm * BM + wr + ls * 4;
    const int c0 = bn * BN + wc + lr;
    #pragma unroll
    for (int n = 0; n < 4; ++n) {
        const int gc = c0 + n * 16;
        const float bv = bias[gc];
        #pragma unroll
        for (int m = 0; m < 8; ++m) {
            #pragma unroll
            for (int j = 0; j < 4; ++j) {
                const int gr = r0 + m * 16 + j;
                const float v = acc[m][n][j] + bv;
                if constexpr (OUT_BF16)
                    ((unsigned short*)Cvoid)[(size_t)gr * N + gc] = f2bf(v);
                else
                    ((float*)Cvoid)[(size_t)gr * N + gc] = v;
            }
        }
    }
}

// ---------------- per-token attention over heads (8x8 softmax) --------------
__global__ __launch_bounds__(256) void attn_heads(
        const unsigned short* __restrict__ qkv,   // [M][1536] bf16
        unsigned short* __restrict__ val,         // [M][512]  bf16
        int M) {
    const int t    = blockIdx.x * 4 + (threadIdx.x >> 6);
    const int lane = threadIdx.x & 63;
    const int h    = lane >> 3;
    const int c    = lane & 7;
    const unsigned short* base = qkv + (size_t)t * 1536;

    s16x8 q8 = *(const s16x8*)(base + h * 192 + c * 8);
    float qf[8];
    #pragma unroll
    for (int j = 0; j < 8; ++j) qf[j] = bf2f((unsigned short)q8[j]);

    float s[8];
    #pragma unroll
    for (int g = 0; g < 8; ++g) {
        s16x8 k8 = *(const s16x8*)(base + g * 192 + 64 + c * 8);
        float p = 0.f;
        #pragma unroll
        for (int j = 0; j < 8; ++j) p += qf[j] * bf2f((unsigned short)k8[j]);
        s[g] = p;
    }
    #pragma unroll
    for (int mask = 1; mask <= 4; mask <<= 1)
        #pragma unroll
        for (int g = 0; g < 8; ++g)
            s[g] += __shfl_xor(s[g], mask, 64);

    float mx = -1e30f;
    #pragma unroll
    for (int g = 0; g < 8; ++g) { s[g] *= 0.125f; mx = fmaxf(mx, s[g]); }
    float sum = 0.f;
    #pragma unroll
    for (int g = 0; g < 8; ++g) { s[g] = __expf(s[g] - mx); sum += s[g]; }
    const float inv = 1.f / sum;

    float acc[8] = {0.f,0.f,0.f,0.f,0.f,0.f,0.f,0.f};
    #pragma unroll
    for (int g = 0; g < 8; ++g) {
        s16x8 v8 = *(const s16x8*)(base + g * 192 + 128 + c * 8);
        const float ag = s[g] * inv;
        #pragma unroll
        for (int j = 0; j < 8; ++j) acc[j] += ag * bf2f((unsigned short)v8[j]);
    }
    s16x8 ov;
    #pragma unroll
    for (int j = 0; j < 8; ++j) ov[j] = (short)f2bf(acc[j]);
    *(s16x8*)(val + (size_t)t * 512 + h * 64 + c * 8) = ov;
}

// ---------------------------------------------------------------------------
extern "C" void kernel_launch(void* const* d_in, const int* in_sizes, int n_in,
                              void* d_out, int out_size, void* d_ws, size_t ws_size,
                              hipStream_t stream) {
    const float* x     = (const float*)d_in[0];
    const float* w_qkv = (const float*)d_in[1];
    const float* b_qkv = (const float*)d_in[2];
    const float* w_out = (const float*)d_in[3];
    const float* b_out = (const float*)d_in[4];
    float* out = (float*)d_out;

    const int DM = 512;
    const int M  = in_sizes[0] / DM;      // 61440 tokens

    unsigned short* xb    = (unsigned short*)d_ws;          // M*512
    unsigned short* wqkvb = xb + (size_t)M * DM;            // 1536*512
    unsigned short* woutb = wqkvb + (size_t)3 * DM * DM;    // 512*512
    unsigned short* qkvb  = woutb + (size_t)DM * DM;        // M*1536
    unsigned short* valb  = xb;   // reuse x_bf16 buffer after GEMM1 consumed it

    cvt_bf16<<<2048, 256, 0, stream>>>(x, xb, M * DM / 4);
    cvt_bf16<<<96,   256, 0, stream>>>(w_qkv, wqkvb, 3 * DM * DM / 4);
    cvt_bf16<<<32,   256, 0, stream>>>(w_out, woutb, DM * DM / 4);

    // GEMM1: qkv[M][1536] = x @ w_qkv^T + b_qkv (bf16 out). grid 240*6=1440
    gemm256<512, true><<<dim3((M / 256) * (3 * DM / 256)), 512, 0, stream>>>(
        xb, wqkvb, b_qkv, qkvb, M, 3 * DM, 3 * DM / 256);

    // per-token attention over heads
    attn_heads<<<M / 4, 256, 0, stream>>>(qkvb, valb, M);

    // GEMM2: out[M][512] = val @ w_out^T + b_out (fp32 out). grid 240*2=480
    gemm256<512, false><<<dim3((M / 256) * (DM / 256)), 512, 0, stream>>>(
        valb, woutb, b_out, out, M, DM, DM / 256);
}

// Round 3
// 314.517 us; speedup vs baseline: 1.0162x; 1.0162x over previous
//
#include <hip/hip_runtime.h>
#include <hip/hip_bf16.h>
#include <stdint.h>

typedef short    s16x8  __attribute__((ext_vector_type(8)));
typedef __bf16   bf16x8 __attribute__((ext_vector_type(8)));
typedef float    f32x4  __attribute__((ext_vector_type(4)));

__device__ __forceinline__ unsigned short f2bf(float f) {
    union { float f; unsigned u; } v; v.f = f;
    unsigned r = v.u + 0x7FFFu + ((v.u >> 16) & 1u);
    return (unsigned short)(r >> 16);
}
__device__ __forceinline__ float bf2f(unsigned short s) {
    union { unsigned u; float f; } v; v.u = ((unsigned)s) << 16;
    return v.f;
}

__device__ __forceinline__ void gload16(const void* g, void* l) {
    __builtin_amdgcn_global_load_lds(
        (const __attribute__((address_space(1))) void*)(uintptr_t)g,
        (__attribute__((address_space(3))) void*)(uintptr_t)l,
        16, 0, 0);
}

// ---------------- fp32 -> bf16 conversion (vectorized, grid-stride) ----------
__global__ __launch_bounds__(256) void cvt_bf16(const float* __restrict__ in,
                                                unsigned short* __restrict__ out,
                                                int n4) {
    int i = blockIdx.x * blockDim.x + threadIdx.x;
    int stride = gridDim.x * blockDim.x;
    for (; i < n4; i += stride) {
        const float4 v = *(const float4*)(in + (size_t)i * 4);
        ushort4 o;
        o.x = f2bf(v.x); o.y = f2bf(v.y); o.z = f2bf(v.z); o.w = f2bf(v.w);
        *(ushort4*)(out + (size_t)i * 4) = o;
    }
}

// ---------------- 256x256 bf16 GEMM:  C = A[M][K] @ B[N][K]^T + bias --------
// 8 waves (2M x 4N), BK=32, 4-slab LDS ring (128 KiB), prefetch depth 3,
// counted vmcnt(8) steady state (T3+T4), XOR LDS swizzle both-sides (T2),
// setprio around MFMA (T5), bijective XCD blockIdx swizzle (T1).
// One raw s_barrier + one counted vmcnt per K-iteration; never drain to 0
// in the main loop (epilogue drains 8 -> 4 -> 0).
template<int K, bool OUT_BF16>
__global__ __launch_bounds__(512, 2) void gemm256(
        const unsigned short* __restrict__ A,   // [M][K] bf16
        const unsigned short* __restrict__ B,   // [N][K] bf16
        const float* __restrict__ bias,         // [N] fp32
        void* __restrict__ Cvoid,               // [M][N] bf16 or fp32
        int M, int N, int ntn) {
    constexpr int BM = 256, BN = 256, BK = 32, NT = K / BK;
    __shared__ unsigned short As[4][BM * BK];   // 4 x 16 KiB
    __shared__ unsigned short Bs[4][BN * BK];   // 4 x 16 KiB
    const int tid  = threadIdx.x;
    const int lane = tid & 63;
    const int wv   = tid >> 6;
    // T1: bijective XCD swizzle (gridDim.x % 8 == 0 guaranteed by launcher)
    const int nwg = (int)gridDim.x;
    const int wg  = ((int)blockIdx.x & 7) * (nwg >> 3) + ((int)blockIdx.x >> 3);
    const int bm  = wg / ntn;
    const int bn  = wg % ntn;
    const int wr  = (wv >> 2) * 128;   // wave M-offset in tile
    const int wc  = (wv & 3) * 64;     // wave N-offset in tile
    const int lr  = lane & 15;
    const int ls  = lane >> 4;         // k-slot 0..3

    const unsigned short* Ag = A + (size_t)bm * BM * K;
    const unsigned short* Bg = B + (size_t)bn * BN * K;

    // Stage K-slab t (256x32 of A and of B). LDS dest linear (wave-uniform
    // base + lane*16); T2 swizzle applied on the GLOBAL source slot (rule #21).
    auto stage = [&](int t) {
        const unsigned short* GA = Ag + t * BK;
        const unsigned short* GB = Bg + t * BK;
        char* la = (char*)As[t & 3];
        char* lb = (char*)Bs[t & 3];
        #pragma unroll
        for (int p = 0; p < 2; ++p) {
            const int c     = p * 512 + tid;
            const int row   = c >> 2;            // 4 x 16B chunks per 64B row
            const int slot  = c & 3;
            const int gslot = slot ^ ((row >> 1) & 3);   // T2 involution
            gload16(GA + (size_t)row * K + gslot * 8, la + c * 16);
            gload16(GB + (size_t)row * K + gslot * 8, lb + c * 16);
        }
    };
    // Read one MFMA fragment: logical k-slot ls, physical = ls ^ swz(row).
    auto frag = [&](const unsigned short* lds, int row) -> bf16x8 {
        const int slot = ls ^ ((row >> 1) & 3);
        return *(const bf16x8*)((const char*)lds + row * (BK * 2) + slot * 16);
    };

    f32x4 acc[8][4] = {};

    stage(0); stage(1); stage(2);      // 12 loads/thread in flight

    #pragma unroll
    for (int t = 0; t < NT; ++t) {
        // own share of slab t landed; slabs t+1, t+2 stay in flight
        if (t <= NT - 3)      asm volatile("s_waitcnt vmcnt(8)" ::: "memory");
        else if (t == NT - 2) asm volatile("s_waitcnt vmcnt(4)" ::: "memory");
        else                  asm volatile("s_waitcnt vmcnt(0)" ::: "memory");
        __builtin_amdgcn_s_barrier();  // all waves' slab-t shares visible; all
                                       // waves done reading ring slot (t+3)&3
        if (t + 3 < NT) stage(t + 3);  // WAR-safe: slot last read at iter t-1

        const unsigned short* la = As[t & 3];
        const unsigned short* lb = Bs[t & 3];
        bf16x8 af[8], bfr[4];
        #pragma unroll
        for (int m = 0; m < 8; ++m) af[m] = frag(la, wr + m * 16 + lr);
        #pragma unroll
        for (int n = 0; n < 4; ++n) bfr[n] = frag(lb, wc + n * 16 + lr);

        __builtin_amdgcn_s_setprio(1);
        #pragma unroll
        for (int m = 0; m < 8; ++m)
            #pragma unroll
            for (int n = 0; n < 4; ++n)
                acc[m][n] = __builtin_amdgcn_mfma_f32_16x16x32_bf16(
                    af[m], bfr[n], acc[m][n], 0, 0, 0);
        __builtin_amdgcn_s_setprio(0);
    }

    // epilogue: C/D layout col=lane&15, row=(lane>>4)*4+j (HW-verified)
    const int r0 = bm * BM + wr + ls * 4;
    const int c0 = bn * BN + wc + lr;
    #pragma unroll
    for (int n = 0; n < 4; ++n) {
        const int gc = c0 + n * 16;
        const float bv = bias[gc];
        #pragma unroll
        for (int m = 0; m < 8; ++m) {
            #pragma unroll
            for (int j = 0; j < 4; ++j) {
                const int gr = r0 + m * 16 + j;
                const float v = acc[m][n][j] + bv;
                if constexpr (OUT_BF16)
                    ((unsigned short*)Cvoid)[(size_t)gr * N + gc] = f2bf(v);
                else
                    ((float*)Cvoid)[(size_t)gr * N + gc] = v;
            }
        }
    }
}

// ---------------- per-token attention over heads (8x8 softmax) --------------
__global__ __launch_bounds__(256) void attn_heads(
        const unsigned short* __restrict__ qkv,   // [M][1536] bf16
        unsigned short* __restrict__ val,         // [M][512]  bf16
        int M) {
    const int t    = blockIdx.x * 4 + (threadIdx.x >> 6);
    const int lane = threadIdx.x & 63;
    const int h    = lane >> 3;
    const int c    = lane & 7;
    const unsigned short* base = qkv + (size_t)t * 1536;

    s16x8 q8 = *(const s16x8*)(base + h * 192 + c * 8);
    float qf[8];
    #pragma unroll
    for (int j = 0; j < 8; ++j) qf[j] = bf2f((unsigned short)q8[j]);

    float s[8];
    #pragma unroll
    for (int g = 0; g < 8; ++g) {
        s16x8 k8 = *(const s16x8*)(base + g * 192 + 64 + c * 8);
        float p = 0.f;
        #pragma unroll
        for (int j = 0; j < 8; ++j) p += qf[j] * bf2f((unsigned short)k8[j]);
        s[g] = p;
    }
    #pragma unroll
    for (int mask = 1; mask <= 4; mask <<= 1)
        #pragma unroll
        for (int g = 0; g < 8; ++g)
            s[g] += __shfl_xor(s[g], mask, 64);

    float mx = -1e30f;
    #pragma unroll
    for (int g = 0; g < 8; ++g) { s[g] *= 0.125f; mx = fmaxf(mx, s[g]); }
    float sum = 0.f;
    #pragma unroll
    for (int g = 0; g < 8; ++g) { s[g] = __expf(s[g] - mx); sum += s[g]; }
    const float inv = 1.f / sum;

    float acc[8] = {0.f,0.f,0.f,0.f,0.f,0.f,0.f,0.f};
    #pragma unroll
    for (int g = 0; g < 8; ++g) {
        s16x8 v8 = *(const s16x8*)(base + g * 192 + 128 + c * 8);
        const float ag = s[g] * inv;
        #pragma unroll
        for (int j = 0; j < 8; ++j) acc[j] += ag * bf2f((unsigned short)v8[j]);
    }
    s16x8 ov;
    #pragma unroll
    for (int j = 0; j < 8; ++j) ov[j] = (short)f2bf(acc[j]);
    *(s16x8*)(val + (size_t)t * 512 + h * 64 + c * 8) = ov;
}

// ---------------------------------------------------------------------------
extern "C" void kernel_launch(void* const* d_in, const int* in_sizes, int n_in,
                              void* d_out, int out_size, void* d_ws, size_t ws_size,
                              hipStream_t stream) {
    const float* x     = (const float*)d_in[0];
    const float* w_qkv = (const float*)d_in[1];
    const float* b_qkv = (const float*)d_in[2];
    const float* w_out = (const float*)d_in[3];
    const float* b_out = (const float*)d_in[4];
    float* out = (float*)d_out;

    const int DM = 512;
    const int M  = in_sizes[0] / DM;      // 61440 tokens

    unsigned short* xb    = (unsigned short*)d_ws;          // M*512
    unsigned short* wqkvb = xb + (size_t)M * DM;            // 1536*512
    unsigned short* woutb = wqkvb + (size_t)3 * DM * DM;    // 512*512
    unsigned short* qkvb  = woutb + (size_t)DM * DM;        // M*1536
    unsigned short* valb  = xb;   // reuse x_bf16 buffer after GEMM1 consumed it

    cvt_bf16<<<2048, 256, 0, stream>>>(x, xb, M * DM / 4);
    cvt_bf16<<<96,   256, 0, stream>>>(w_qkv, wqkvb, 3 * DM * DM / 4);
    cvt_bf16<<<32,   256, 0, stream>>>(w_out, woutb, DM * DM / 4);

    // GEMM1: qkv[M][1536] = x @ w_qkv^T + b_qkv (bf16 out). grid 240*6=1440
    gemm256<512, true><<<dim3((M / 256) * (3 * DM / 256)), 512, 0, stream>>>(
        xb, wqkvb, b_qkv, qkvb, M, 3 * DM, 3 * DM / 256);

    // per-token attention over heads
    attn_heads<<<M / 4, 256, 0, stream>>>(qkvb, valb, M);

    // GEMM2: out[M][512] = val @ w_out^T + b_out (fp32 out). grid 240*2=480
    gemm256<512, false><<<dim3((M / 256) * (DM / 256)), 512, 0, stream>>>(
        valb, woutb, b_out, out, M, DM, DM / 256);
}

// Round 4
// 314.435 us; speedup vs baseline: 1.0165x; 1.0003x over previous
//
#include <hip/hip_runtime.h>
#include <hip/hip_bf16.h>
#include <stdint.h>

typedef short    s16x8  __attribute__((ext_vector_type(8)));
typedef __bf16   bf16x8 __attribute__((ext_vector_type(8)));
typedef float    f32x4  __attribute__((ext_vector_type(4)));

__device__ __forceinline__ unsigned short f2bf(float f) {
    union { float f; unsigned u; } v; v.f = f;
    unsigned r = v.u + 0x7FFFu + ((v.u >> 16) & 1u);
    return (unsigned short)(r >> 16);
}
__device__ __forceinline__ float bf2f(unsigned short s) {
    union { unsigned u; float f; } v; v.u = ((unsigned)s) << 16;
    return v.f;
}

__device__ __forceinline__ void gload16(const void* g, void* l) {
    __builtin_amdgcn_global_load_lds(
        (const __attribute__((address_space(1))) void*)(uintptr_t)g,
        (__attribute__((address_space(3))) void*)(uintptr_t)l,
        16, 0, 0);
}

// ---------------- fp32 -> bf16 conversion (vectorized, grid-stride) ----------
__global__ __launch_bounds__(256) void cvt_bf16(const float* __restrict__ in,
                                                unsigned short* __restrict__ out,
                                                int n4) {
    int i = blockIdx.x * blockDim.x + threadIdx.x;
    int stride = gridDim.x * blockDim.x;
    for (; i < n4; i += stride) {
        const float4 v = *(const float4*)(in + (size_t)i * 4);
        ushort4 o;
        o.x = f2bf(v.x); o.y = f2bf(v.y); o.z = f2bf(v.z); o.w = f2bf(v.w);
        *(ushort4*)(out + (size_t)i * 4) = o;
    }
}

// ---------------- 256x256 bf16 GEMM:  C = A[M][K] @ B[N][K]^T + bias --------
// Fine-phase schedule (m196/m201 mechanism): 2 phases per BK=32 K-tile, each
// phase = {half-stage issue (2 gload_lds), next operands' ds_reads, setprio,
// 16 MFMA, setprio, barrier}. Operand ds_reads run ONE PHASE AHEAD so the
// compiler's dataflow lgkmcnt is a counted wait. 4-slot LDS ring (128 KiB),
// prefetch distance 3 tiles, one counted vmcnt(8) per tile (tail 4 -> 0).
// T2 XOR swizzle both-sides (conflicts measured 0), T5 setprio, T1 XCD swizzle.
template<int K, bool OUT_BF16>
__global__ __launch_bounds__(512, 2) void gemm256(
        const unsigned short* __restrict__ A,   // [M][K] bf16
        const unsigned short* __restrict__ B,   // [N][K] bf16
        const float* __restrict__ bias,         // [N] fp32
        void* __restrict__ Cvoid,               // [M][N] bf16 or fp32
        int M, int N, int ntn) {
    constexpr int BM = 256, BN = 256, BK = 32, NT = K / BK;
    __shared__ unsigned short As[4][BM * BK];   // 4 x 16 KiB
    __shared__ unsigned short Bs[4][BN * BK];   // 4 x 16 KiB
    const int tid  = threadIdx.x;
    const int lane = tid & 63;
    const int wv   = tid >> 6;
    const int nwg = (int)gridDim.x;
    const int wg  = ((int)blockIdx.x & 7) * (nwg >> 3) + ((int)blockIdx.x >> 3);
    const int bm  = wg / ntn;
    const int bn  = wg % ntn;
    const int wr  = (wv >> 2) * 128;   // wave M-offset in tile
    const int wc  = (wv & 3) * 64;     // wave N-offset in tile
    const int lr  = lane & 15;
    const int ls  = lane >> 4;         // k-slot 0..3

    const unsigned short* Ag = A + (size_t)bm * BM * K;
    const unsigned short* Bg = B + (size_t)bn * BN * K;

    // Stage half h (rows h*128..h*128+127) of K-slab t for both A and B.
    // LDS dest linear (wave-uniform base + lane*16); T2 swizzle pre-applied
    // on the GLOBAL source slot (rule #21).
    auto stage_half = [&](int t, int h) {
        const unsigned short* GA = Ag + t * BK;
        const unsigned short* GB = Bg + t * BK;
        char* la = (char*)As[t & 3];
        char* lb = (char*)Bs[t & 3];
        const int c     = h * 512 + tid;
        const int row   = c >> 2;                    // 4 x 16B chunks per row
        const int slot  = c & 3;
        const int gslot = slot ^ ((row >> 1) & 3);   // T2 involution
        gload16(GA + (size_t)row * K + gslot * 8, la + c * 16);
        gload16(GB + (size_t)row * K + gslot * 8, lb + c * 16);
    };
    // Read one MFMA fragment: logical k-slot ls, physical = ls ^ swz(row).
    auto frag = [&](const unsigned short* lds, int row) -> bf16x8 {
        const int slot = ls ^ ((row >> 1) & 3);
        return *(const bf16x8*)((const char*)lds + row * (BK * 2) + slot * 16);
    };

    f32x4 acc[8][4] = {};
    bf16x8 bfr[2][4];     // tile-parity B fragments (static index after unroll)
    bf16x8 af0[4], af1[4];

    stage_half(0, 0); stage_half(0, 1);
    stage_half(1, 0); stage_half(1, 1);
    stage_half(2, 0); stage_half(2, 1);            // 12 loads/thread in flight
    asm volatile("s_waitcnt vmcnt(8)" ::: "memory"); // tile 0 landed
    __builtin_amdgcn_s_barrier();                    // tile 0 published
    #pragma unroll
    for (int n = 0; n < 4; ++n) bfr[0][n] = frag(Bs[0], wc + n * 16 + lr);
    #pragma unroll
    for (int m = 0; m < 4; ++m) af0[m] = frag(As[0], wr + m * 16 + lr);

    #pragma unroll
    for (int t = 0; t < NT; ++t) {
        const int cur = t & 1, nxt = cur ^ 1;
        // ---- PH0: compute acc[0..3] with af0(t) x bfr(t); read af1(t) ----
        if (t + 3 < NT) stage_half(t + 3, 0);   // slot (t-1)&3: WAR-safe, all
                                                // reads done before barrier-C(t-1)
        #pragma unroll
        for (int m = 0; m < 4; ++m) af1[m] = frag(As[t & 3], wr + 64 + m * 16 + lr);
        __builtin_amdgcn_s_setprio(1);
        #pragma unroll
        for (int m = 0; m < 4; ++m)
            #pragma unroll
            for (int n = 0; n < 4; ++n)
                acc[m][n] = __builtin_amdgcn_mfma_f32_16x16x32_bf16(
                    af0[m], bfr[cur][n], acc[m][n], 0, 0, 0);
        __builtin_amdgcn_s_setprio(0);
        __builtin_amdgcn_s_barrier();           // [A] phase boundary

        // ---- PH1: compute acc[4..7] with af1(t) x bfr(t); read tile t+1 ----
        if (t + 3 < NT) stage_half(t + 3, 1);
        if (t + 1 < NT) {
            // publish tile t+1 (issued at tile t-2; 8 newer loads in flight)
            if (t <= NT - 4)      asm volatile("s_waitcnt vmcnt(8)" ::: "memory");
            else if (t == NT - 3) asm volatile("s_waitcnt vmcnt(4)" ::: "memory");
            else                  asm volatile("s_waitcnt vmcnt(0)" ::: "memory");
            __builtin_amdgcn_s_barrier();       // [B] tile t+1 visible to all
            #pragma unroll
            for (int n = 0; n < 4; ++n)
                bfr[nxt][n] = frag(Bs[(t + 1) & 3], wc + n * 16 + lr);
            #pragma unroll
            for (int m = 0; m < 4; ++m)
                af0[m] = frag(As[(t + 1) & 3], wr + m * 16 + lr);
        }
        __builtin_amdgcn_s_setprio(1);
        #pragma unroll
        for (int m = 0; m < 4; ++m)
            #pragma unroll
            for (int n = 0; n < 4; ++n)
                acc[4 + m][n] = __builtin_amdgcn_mfma_f32_16x16x32_bf16(
                    af1[m], bfr[cur][n], acc[4 + m][n], 0, 0, 0);
        __builtin_amdgcn_s_setprio(0);
        __builtin_amdgcn_s_barrier();           // [C] all reads of slot t&3 done
    }

    // epilogue: C/D layout col=lane&15, row=(lane>>4)*4+j (HW-verified)
    const int r0 = bm * BM + wr + ls * 4;
    const int c0 = bn * BN + wc + lr;
    #pragma unroll
    for (int n = 0; n < 4; ++n) {
        const int gc = c0 + n * 16;
        const float bv = bias[gc];
        #pragma unroll
        for (int m = 0; m < 8; ++m) {
            #pragma unroll
            for (int j = 0; j < 4; ++j) {
                const int gr = r0 + m * 16 + j;
                const float v = acc[m][n][j] + bv;
                if constexpr (OUT_BF16)
                    ((unsigned short*)Cvoid)[(size_t)gr * N + gc] = f2bf(v);
                else
                    ((float*)Cvoid)[(size_t)gr * N + gc] = v;
            }
        }
    }
}

// ---------------- per-token attention over heads (8x8 softmax) --------------
__global__ __launch_bounds__(256) void attn_heads(
        const unsigned short* __restrict__ qkv,   // [M][1536] bf16
        unsigned short* __restrict__ val,         // [M][512]  bf16
        int M) {
    const int t    = blockIdx.x * 4 + (threadIdx.x >> 6);
    const int lane = threadIdx.x & 63;
    const int h    = lane >> 3;
    const int c    = lane & 7;
    const unsigned short* base = qkv + (size_t)t * 1536;

    s16x8 q8 = *(const s16x8*)(base + h * 192 + c * 8);
    float qf[8];
    #pragma unroll
    for (int j = 0; j < 8; ++j) qf[j] = bf2f((unsigned short)q8[j]);

    float s[8];
    #pragma unroll
    for (int g = 0; g < 8; ++g) {
        s16x8 k8 = *(const s16x8*)(base + g * 192 + 64 + c * 8);
        float p = 0.f;
        #pragma unroll
        for (int j = 0; j < 8; ++j) p += qf[j] * bf2f((unsigned short)k8[j]);
        s[g] = p;
    }
    #pragma unroll
    for (int mask = 1; mask <= 4; mask <<= 1)
        #pragma unroll
        for (int g = 0; g < 8; ++g)
            s[g] += __shfl_xor(s[g], mask, 64);

    float mx = -1e30f;
    #pragma unroll
    for (int g = 0; g < 8; ++g) { s[g] *= 0.125f; mx = fmaxf(mx, s[g]); }
    float sum = 0.f;
    #pragma unroll
    for (int g = 0; g < 8; ++g) { s[g] = __expf(s[g] - mx); sum += s[g]; }
    const float inv = 1.f / sum;

    float acc[8] = {0.f,0.f,0.f,0.f,0.f,0.f,0.f,0.f};
    #pragma unroll
    for (int g = 0; g < 8; ++g) {
        s16x8 v8 = *(const s16x8*)(base + g * 192 + 128 + c * 8);
        const float ag = s[g] * inv;
        #pragma unroll
        for (int j = 0; j < 8; ++j) acc[j] += ag * bf2f((unsigned short)v8[j]);
    }
    s16x8 ov;
    #pragma unroll
    for (int j = 0; j < 8; ++j) ov[j] = (short)f2bf(acc[j]);
    *(s16x8*)(val + (size_t)t * 512 + h * 64 + c * 8) = ov;
}

// ---------------------------------------------------------------------------
extern "C" void kernel_launch(void* const* d_in, const int* in_sizes, int n_in,
                              void* d_out, int out_size, void* d_ws, size_t ws_size,
                              hipStream_t stream) {
    const float* x     = (const float*)d_in[0];
    const float* w_qkv = (const float*)d_in[1];
    const float* b_qkv = (const float*)d_in[2];
    const float* w_out = (const float*)d_in[3];
    const float* b_out = (const float*)d_in[4];
    float* out = (float*)d_out;

    const int DM = 512;
    const int M  = in_sizes[0] / DM;      // 61440 tokens

    unsigned short* xb    = (unsigned short*)d_ws;          // M*512
    unsigned short* wqkvb = xb + (size_t)M * DM;            // 1536*512
    unsigned short* woutb = wqkvb + (size_t)3 * DM * DM;    // 512*512
    unsigned short* qkvb  = woutb + (size_t)DM * DM;        // M*1536
    unsigned short* valb  = xb;   // reuse x_bf16 buffer after GEMM1 consumed it

    cvt_bf16<<<2048, 256, 0, stream>>>(x, xb, M * DM / 4);
    cvt_bf16<<<96,   256, 0, stream>>>(w_qkv, wqkvb, 3 * DM * DM / 4);
    cvt_bf16<<<32,   256, 0, stream>>>(w_out, woutb, DM * DM / 4);

    // GEMM1: qkv[M][1536] = x @ w_qkv^T + b_qkv (bf16 out). grid 240*6=1440
    gemm256<512, true><<<dim3((M / 256) * (3 * DM / 256)), 512, 0, stream>>>(
        xb, wqkvb, b_qkv, qkvb, M, 3 * DM, 3 * DM / 256);

    // per-token attention over heads
    attn_heads<<<M / 4, 256, 0, stream>>>(qkvb, valb, M);

    // GEMM2: out[M][512] = val @ w_out^T + b_out (fp32 out). grid 240*2=480
    gemm256<512, false><<<dim3((M / 256) * (DM / 256)), 512, 0, stream>>>(
        valb, woutb, b_out, out, M, DM, DM / 256);
}